// Round 1
// baseline (190.354 us; speedup 1.0000x reference)
//
#include <hip/hip_runtime.h>

#define NVAL 15
#define TPB  256
#define VPT  8   // float4 loads per thread; pinned in-flight together via sched_barrier

typedef float fvec4 __attribute__((ext_vector_type(4)));

__device__ __forceinline__ fvec4 quant4(fvec4 v, const float* tf, float sc1, float k)
{
    float xs0 = v.x * sc1, xs1 = v.y * sc1, xs2 = v.z * sc1, xs3 = v.w * sc1;
    int c0 = 0, c1 = 0, c2 = 0, c3 = 0;
#pragma unroll
    for (int i = 0; i < NVAL; ++i) {
        float t = tf[i];
        c0 += (xs0 > t);   // strict > : searchsorted side="left"
        c1 += (xs1 > t);
        c2 += (xs2 > t);
        c3 += (xs3 > t);
    }
    fvec4 r;
    r.x = k * (float)c0;
    r.y = k * (float)c1;
    r.z = k * (float)c2;
    r.w = k * (float)c3;
    return r;
}

// Exact-fit main kernel. Each block owns a contiguous 32 KB span. The 8 loads
// are issued BEFORE the scheduling barrier so the compiler cannot sink them to
// their uses (R4's VGPR=36 proved it was doing exactly that): 8 KB per wave
// genuinely outstanding. Threshold setup happens under load latency.
//
// R5 change (single variable): PLAIN loads instead of __builtin_nontemporal_load.
// Rationale: the 6.29 TB/s m13 ceiling was measured with plain float4 loads;
// nt (evict-first) is the only deviation from that proven read path. The
// original "protect LLC for write absorption" rationale is void: x + out =
// 205.5 MB < 256 MB MALL, both streams fit simultaneously.
__global__ __launch_bounds__(TPB) void ltq_main(
    const float* __restrict__ x,
    const float* __restrict__ start,
    const float* __restrict__ a,
    const float* __restrict__ scale1,
    const float* __restrict__ scale2,
    float* __restrict__ out)
{
    const long long base = (long long)blockIdx.x * (TPB * VPT) + threadIdx.x;
    const fvec4* __restrict__ x4 = (const fvec4*)x + base;
    fvec4* __restrict__ o4 = (fvec4*)out + base;

    fvec4 v[VPT];
#pragma unroll
    for (int j = 0; j < VPT; ++j)
        v[j] = x4[j * TPB];                      // plain load: match m13's measured-ceiling pattern

    __builtin_amdgcn_sched_barrier(0);  // pin: all 8 loads issued before any compute

    // threshold setup overlaps the in-flight loads
    const float s   = start[0];
    const float sc1 = scale1[0];
    const float k   = (float)(2.0 / 15.0) * scale2[0];
    float tf[NVAL];
    float cum = 0.0f;
#pragma unroll
    for (int i = 0; i < NVAL; ++i) {
        float ai = a[i];
        float ap = (ai > 1e-3f) ? ai : 1e-3f;   // jnp.where(a > EPS, a, EPS)
        tf[i] = (s + cum) + 0.5f * ap;          // tb[i] + a_pos[i]/2, exact fp32 association
        cum += ap;                              // sequential cumsum, matches np
    }

#pragma unroll
    for (int j = 0; j < VPT; ++j) {
        fvec4 r = quant4(v[j], tf, sc1, k);
        o4[j * TPB] = r;                         // regular store: LLC absorbs writes
    }
}

// Generic tail (not launched when the main grid tiles n exactly — true here).
__global__ __launch_bounds__(TPB) void ltq_tail(
    const float* __restrict__ x,
    const float* __restrict__ start,
    const float* __restrict__ a,
    const float* __restrict__ scale1,
    const float* __restrict__ scale2,
    float* __restrict__ out,
    long long f4_done, long long n4, long long n)
{
    const float s   = start[0];
    const float sc1 = scale1[0];
    const float k   = (float)(2.0 / 15.0) * scale2[0];
    float tf[NVAL];
    float cum = 0.0f;
#pragma unroll
    for (int i = 0; i < NVAL; ++i) {
        float ai = a[i];
        float ap = (ai > 1e-3f) ? ai : 1e-3f;
        tf[i] = (s + cum) + 0.5f * ap;
        cum += ap;
    }

    const long long stride = (long long)gridDim.x * blockDim.x;
    const fvec4* __restrict__ x4 = (const fvec4*)x;
    fvec4* __restrict__ o4 = (fvec4*)out;
    for (long long i = f4_done + blockIdx.x * (long long)blockDim.x + threadIdx.x;
         i < n4; i += stride) {
        o4[i] = quant4(x4[i], tf, sc1, k);
    }
    for (long long i = (n4 << 2) + blockIdx.x * (long long)blockDim.x + threadIdx.x;
         i < n; i += stride) {
        float xs = x[i] * sc1;
        int c = 0;
#pragma unroll
        for (int t = 0; t < NVAL; ++t) c += (xs > tf[t]);
        out[i] = k * (float)c;
    }
}

extern "C" void kernel_launch(void* const* d_in, const int* in_sizes, int n_in,
                              void* d_out, int out_size, void* d_ws, size_t ws_size,
                              hipStream_t stream) {
    const float* x      = (const float*)d_in[0];
    const float* start  = (const float*)d_in[1];
    const float* a      = (const float*)d_in[2];
    const float* scale1 = (const float*)d_in[3];
    const float* scale2 = (const float*)d_in[4];
    float* out = (float*)d_out;

    const long long n  = in_sizes[0];
    const long long n4 = n >> 2;
    const long long per_block = (long long)TPB * VPT;      // float4s per block
    const long long blocks = n4 / per_block;               // exact-fit main grid

    if (blocks > 0) {
        // N=25,690,112 -> n4=6,422,528 -> 3136 blocks, zero remainder.
        ltq_main<<<(int)blocks, TPB, 0, stream>>>(x, start, a, scale1, scale2, out);
    }
    const long long f4_done = blocks * per_block;
    if (f4_done < n4 || (n & 3)) {
        ltq_tail<<<512, TPB, 0, stream>>>(x, start, a, scale1, scale2, out,
                                          f4_done, n4, n);
    }
}

// Round 2
// 178.063 us; speedup vs baseline: 1.0690x; 1.0690x over previous
//
#include <hip/hip_runtime.h>

#define NVAL 15
#define TPB  256
#define VPT  4   // float4 loads per thread — sized so data(16)+tf(15)+addr fits VGPRs

typedef float fvec4 __attribute__((ext_vector_type(4)));

__device__ __forceinline__ fvec4 quant4(fvec4 v, const float* tf, float sc1, float k)
{
    float xs0 = v.x * sc1, xs1 = v.y * sc1, xs2 = v.z * sc1, xs3 = v.w * sc1;
    int c0 = 0, c1 = 0, c2 = 0, c3 = 0;
#pragma unroll
    for (int i = 0; i < NVAL; ++i) {
        float t = tf[i];
        c0 += (xs0 > t);   // strict > : searchsorted side="left"
        c1 += (xs1 > t);
        c2 += (xs2 > t);
        c3 += (xs3 > t);
    }
    fvec4 r;
    r.x = k * (float)c0;
    r.y = k * (float)c1;
    r.z = k * (float)c2;
    r.w = k * (float)c3;
    return r;
}

// Exact-fit main kernel. R6 changes:
//  1. NT loads RESTORED — R5 A/B proved plain loads regress (+8.5 µs total,
//     kernel 58→64.5 µs). Model: NT keeps x out of the LLC so the LLC can
//     absorb the output write-allocate lines during the kernel window; plain
//     loads evict dirty out-lines and force mid-kernel writebacks.
//  2. VPT 8→4 — R5's VGPR_Count=36 proves 8 outstanding float4s never fit in
//     registers (needs ≥50 live); RA was serializing the "pinned" load burst
//     with waits+copies. 4 loads (16 regs) + tf(15) + addr fits ~40 VGPRs, so
//     the in-flight window is real this time. Still ≤64 VGPR → 8 waves/SIMD.
__global__ __launch_bounds__(TPB) void ltq_main(
    const float* __restrict__ x,
    const float* __restrict__ start,
    const float* __restrict__ a,
    const float* __restrict__ scale1,
    const float* __restrict__ scale2,
    float* __restrict__ out)
{
    const long long base = (long long)blockIdx.x * (TPB * VPT) + threadIdx.x;
    const fvec4* __restrict__ x4 = (const fvec4*)x + base;
    fvec4* __restrict__ o4 = (fvec4*)out + base;

    fvec4 v[VPT];
#pragma unroll
    for (int j = 0; j < VPT; ++j)
        v[j] = __builtin_nontemporal_load(&x4[j * TPB]);  // x never re-read: keep LLC for writes

    __builtin_amdgcn_sched_barrier(0);  // pin: all loads issued before any compute

    // threshold setup overlaps the in-flight loads
    const float s   = start[0];
    const float sc1 = scale1[0];
    const float k   = (float)(2.0 / 15.0) * scale2[0];
    float tf[NVAL];
    float cum = 0.0f;
#pragma unroll
    for (int i = 0; i < NVAL; ++i) {
        float ai = a[i];
        float ap = (ai > 1e-3f) ? ai : 1e-3f;   // jnp.where(a > EPS, a, EPS)
        tf[i] = (s + cum) + 0.5f * ap;          // tb[i] + a_pos[i]/2, exact fp32 association
        cum += ap;                              // sequential cumsum, matches np
    }

#pragma unroll
    for (int j = 0; j < VPT; ++j) {
        fvec4 r = quant4(v[j], tf, sc1, k);
        o4[j * TPB] = r;                         // regular store: LLC absorbs writes
    }
}

// Generic tail (not launched when the main grid tiles n exactly — true here).
__global__ __launch_bounds__(TPB) void ltq_tail(
    const float* __restrict__ x,
    const float* __restrict__ start,
    const float* __restrict__ a,
    const float* __restrict__ scale1,
    const float* __restrict__ scale2,
    float* __restrict__ out,
    long long f4_done, long long n4, long long n)
{
    const float s   = start[0];
    const float sc1 = scale1[0];
    const float k   = (float)(2.0 / 15.0) * scale2[0];
    float tf[NVAL];
    float cum = 0.0f;
#pragma unroll
    for (int i = 0; i < NVAL; ++i) {
        float ai = a[i];
        float ap = (ai > 1e-3f) ? ai : 1e-3f;
        tf[i] = (s + cum) + 0.5f * ap;
        cum += ap;
    }

    const long long stride = (long long)gridDim.x * blockDim.x;
    const fvec4* __restrict__ x4 = (const fvec4*)x;
    fvec4* __restrict__ o4 = (fvec4*)out;
    for (long long i = f4_done + blockIdx.x * (long long)blockDim.x + threadIdx.x;
         i < n4; i += stride) {
        o4[i] = quant4(x4[i], tf, sc1, k);
    }
    for (long long i = (n4 << 2) + blockIdx.x * (long long)blockDim.x + threadIdx.x;
         i < n; i += stride) {
        float xs = x[i] * sc1;
        int c = 0;
#pragma unroll
        for (int t = 0; t < NVAL; ++t) c += (xs > tf[t]);
        out[i] = k * (float)c;
    }
}

extern "C" void kernel_launch(void* const* d_in, const int* in_sizes, int n_in,
                              void* d_out, int out_size, void* d_ws, size_t ws_size,
                              hipStream_t stream) {
    const float* x      = (const float*)d_in[0];
    const float* start  = (const float*)d_in[1];
    const float* a      = (const float*)d_in[2];
    const float* scale1 = (const float*)d_in[3];
    const float* scale2 = (const float*)d_in[4];
    float* out = (float*)d_out;

    const long long n  = in_sizes[0];
    const long long n4 = n >> 2;
    const long long per_block = (long long)TPB * VPT;      // float4s per block
    const long long blocks = n4 / per_block;               // exact-fit main grid

    if (blocks > 0) {
        // N=25,690,112 -> n4=6,422,528 -> 6272 blocks, zero remainder.
        ltq_main<<<(int)blocks, TPB, 0, stream>>>(x, start, a, scale1, scale2, out);
    }
    const long long f4_done = blocks * per_block;
    if (f4_done < n4 || (n & 3)) {
        ltq_tail<<<512, TPB, 0, stream>>>(x, start, a, scale1, scale2, out,
                                          f4_done, n4, n);
    }
}